// Round 1
// baseline (185.648 us; speedup 1.0000x reference)
//
#include <hip/hip_runtime.h>

// LearnedPositionalBias: out[n,h,i,j] = sum_d Q[n,h,i,d] * R[h,d, clamp(j-i,-511,511)+512]
// n=4 h=16 L=1024 d=64, table width 1025, max_positions=512.
//
// Decomposition:
//   t = j - i + 512 in [1,1023]  <=> no clamping; (i,t) -> j injective  => GEMM + diagonal scatter
//   j <= i-512  => out = logits[i,1]       (row constant)
//   j >= i+512  => out = logits[i,1023]    (row constant)

#define NB 4
#define NH 16
#define LQ 1024
#define DD 64
#define TT 1025
#define MAXP 512

#define BI 128          // i rows per block
#define BT 112          // table columns per block
#define QS_STRIDE 65    // pad to avoid bank conflicts

// grid: (t_tiles=10, i_tiles=8, nh=64), block 256 threads
__global__ __launch_bounds__(256, 2) void lpb_main(const float* __restrict__ Q,
                                                   const float* __restrict__ R,
                                                   float* __restrict__ out) {
    const int tt  = blockIdx.x;
    const int it  = blockIdx.y;
    const int nh  = blockIdx.z;
    const int h   = nh & (NH - 1);
    const int tid = threadIdx.x;
    const int tj  = tid & 15;   // 16 threads along t
    const int ti  = tid >> 4;   // 16 threads along i

    const int i0 = it * BI;
    const int t0 = 1 + tt * BT;

    // dead-tile early exit: j = i + t - 512
    {
        const int jmin = i0 + t0 - MAXP;
        const int jmax = i0 + (BI - 1) + t0 + (BT - 1) - MAXP;
        if (jmax < 0 || jmin >= LQ) return;
    }

    __shared__ float Qs[BI][QS_STRIDE];  // [i_local][d], padded stride 65
    __shared__ float Rs[DD][BT];         // [d][t_local]

    // stage Q tile: coalesced global read, 2-way (free) LDS write
    {
        const float* qbase = Q + ((size_t)nh * LQ + i0) * DD;
        for (int idx = tid; idx < BI * DD; idx += 256) {
            const int il = idx >> 6;
            const int d  = idx & 63;
            Qs[il][d] = qbase[il * DD + d];
        }
    }
    // stage R tile: coalesced along t
    {
        const float* rbase = R + (size_t)h * DD * TT;
        for (int idx = tid; idx < DD * BT; idx += 256) {
            const int d  = idx / BT;
            const int tl = idx - d * BT;
            int t = t0 + tl;
            if (t > TT - 1) t = TT - 1;   // guard OOB on last tile (values unused)
            Rs[d][tl] = rbase[d * TT + t];
        }
    }
    __syncthreads();

    // micro-tile: 8 i (contiguous, ti*8+ii) x 7 t (interleaved, jj*16+tj)
    float acc[8][7];
    #pragma unroll
    for (int ii = 0; ii < 8; ++ii)
        #pragma unroll
        for (int jj = 0; jj < 7; ++jj) acc[ii][jj] = 0.f;

    #pragma unroll 4
    for (int d = 0; d < DD; ++d) {
        float qv[8], rv[7];
        #pragma unroll
        for (int ii = 0; ii < 8; ++ii) qv[ii] = Qs[ti * 8 + ii][d];
        #pragma unroll
        for (int jj = 0; jj < 7; ++jj) rv[jj] = Rs[d][jj * 16 + tj];
        #pragma unroll
        for (int ii = 0; ii < 8; ++ii)
            #pragma unroll
            for (int jj = 0; jj < 7; ++jj)
                acc[ii][jj] = fmaf(qv[ii], rv[jj], acc[ii][jj]);
    }

    // scatter: out[nh, i, i + t - 512]
    float* obase = out + (size_t)nh * LQ * LQ;
    #pragma unroll
    for (int ii = 0; ii < 8; ++ii) {
        const int i = i0 + ti * 8 + ii;
        float* orow = obase + (size_t)i * LQ;
        #pragma unroll
        for (int jj = 0; jj < 7; ++jj) {
            const int t = t0 + jj * 16 + tj;
            const int j = i + t - MAXP;
            if (t <= TT - 2 && j >= 0 && j < LQ) orow[j] = acc[ii][jj];
        }
    }
}

// Clamped triangles: left j in [0, i-512] = dot(Q[i],R[:,1]); right j in [i+512, 1023] = dot(Q[i],R[:,1023])
// grid: (256, 64), block 256 (4 waves, one row each)
__global__ __launch_bounds__(256) void lpb_fill(const float* __restrict__ Q,
                                                const float* __restrict__ R,
                                                float* __restrict__ out) {
    const int w    = threadIdx.x >> 6;
    const int lane = threadIdx.x & 63;
    const int i    = blockIdx.x * 4 + w;
    const int nh   = blockIdx.y;
    const int h    = nh & (NH - 1);

    const float q  = Q[((size_t)nh * LQ + i) * DD + lane];
    const float r1 = R[((size_t)h * DD + lane) * TT + 1];
    const float r2 = R[((size_t)h * DD + lane) * TT + (TT - 2)];
    float p1 = q * r1;
    float p2 = q * r2;
    #pragma unroll
    for (int off = 32; off >= 1; off >>= 1) {
        p1 += __shfl_xor(p1, off, 64);
        p2 += __shfl_xor(p2, off, 64);
    }

    float* orow = out + ((size_t)nh * LQ + i) * LQ;
    for (int j = lane; j <= i - MAXP; j += 64) orow[j] = p1;          // j <= i-512
    for (int j = i + MAXP + lane; j < LQ; j += 64) orow[j] = p2;      // j >= i+512
}

extern "C" void kernel_launch(void* const* d_in, const int* in_sizes, int n_in,
                              void* d_out, int out_size, void* d_ws, size_t ws_size,
                              hipStream_t stream) {
    const float* Q = (const float*)d_in[0];
    const float* R = (const float*)d_in[1];
    float* out = (float*)d_out;

    // interior (unclamped diagonals) via tiled GEMM + scatter
    lpb_main<<<dim3(10, 8, NB * NH), 256, 0, stream>>>(Q, R, out);
    // clamped triangles (row constants)
    lpb_fill<<<dim3(LQ / 4, NB * NH), 256, 0, stream>>>(Q, R, out);
}

// Round 2
// 129.021 us; speedup vs baseline: 1.4389x; 1.4389x over previous
//
#include <hip/hip_runtime.h>
#include <hip/hip_bf16.h>

// out[n,h,i,j] = sum_d Q[n,h,i,d] * R[h,d, clamp(j-i,-511,511)+512]
// n=4 h=16 L=1024 d=64, table width 1025.
// Interior (t = j-i+512 in [1,1023]): bf16 MFMA GEMM logits[i][t], scattered to j = i+t-512.
// Clamped triangles: row constants logits[i][1] / logits[i][1023] via lpb_fill.

#define NH 16
#define LQ 1024
#define DD 64
#define TT 1025
#define MAXP 512

typedef float f32x4 __attribute__((ext_vector_type(4)));
typedef short s16x8 __attribute__((ext_vector_type(8)));

__device__ __forceinline__ short f2bf(float f) {
    __hip_bfloat16 h = __float2bfloat16(f);   // RNE
    return __builtin_bit_cast(short, h);
}

// grid: (tt=2, i_tiles=64, nh=64), block 256 = 4 waves.
// Block covers i in [ib*16, ib*16+16), t in [1+tt*512, +512); wave w owns 128 t.
// Per wave: 8 MFMA tiles (16i x 16t, K=64 via two 16x16x32 bf16 MFMAs).
__global__ __launch_bounds__(256, 4) void lpb_main(const float* __restrict__ Q,
                                                   const float* __restrict__ R,
                                                   float* __restrict__ out) {
    const int tt = blockIdx.x;
    const int ib = blockIdx.y;
    const int nh = blockIdx.z;
    const int h  = nh & (NH - 1);
    const int tid = threadIdx.x;
    const int w = tid >> 6;
    const int l = tid & 63;
    const int n = l & 15;      // lane low 4 bits: i-local for A, t-local for B
    const int g = l >> 4;      // lane group 0..3 -> k-chunk 8g..8g+7

    const int ibase  = ib * 16;
    const int t_wave = 1 + tt * 512 + w * 128;

    // ---- A fragments: lane holds Q[ibase+n][kh*32 + 8g + r], r=0..7 (two k-halves)
    const float* qrow = Q + ((size_t)nh * LQ + (ibase + n)) * DD + 8 * g;
    s16x8 qf[2];
    #pragma unroll
    for (int kh = 0; kh < 2; ++kh) {
        f32x4 a = *(const f32x4*)(qrow + kh * 32);
        f32x4 b = *(const f32x4*)(qrow + kh * 32 + 4);
        #pragma unroll
        for (int r = 0; r < 4; ++r) { qf[kh][r] = f2bf(a[r]); qf[kh][4 + r] = f2bf(b[r]); }
    }

    // ---- B fragment base: lane needs R[h][kh*32 + 8g + r][tb + n]
    const float* rcol = R + (size_t)h * DD * TT + (size_t)(8 * g) * TT + (t_wave + n);

    f32x4 acc[8];
    #pragma unroll
    for (int mt = 0; mt < 8; ++mt) {
        acc[mt] = (f32x4){0.f, 0.f, 0.f, 0.f};
        const int tb  = t_wave + mt * 16;
        const int jlo = ibase + tb - MAXP;        // min j in this 16x16 tile
        if (jlo + 30 < 0 || jlo >= LQ) continue;  // wave-uniform dead-tile skip

        s16x8 rf0, rf1;
        #pragma unroll
        for (int r = 0; r < 8; ++r) {
            float v0 = rcol[(size_t)r * TT + mt * 16];
            float v1 = rcol[(size_t)(32 + r) * TT + mt * 16];
            rf0[r] = f2bf(v0);
            rf1[r] = f2bf(v1);
        }
        acc[mt] = __builtin_amdgcn_mfma_f32_16x16x32_bf16(qf[0], rf0, acc[mt], 0, 0, 0);
        acc[mt] = __builtin_amdgcn_mfma_f32_16x16x32_bf16(qf[1], rf1, acc[mt], 0, 0, 0);
    }

    // ---- scatter: D col = n (t-local), row = 4g+s (i-local); out[i][j], j = i + t - 512
    float* obase = out + (size_t)nh * LQ * LQ;
    #pragma unroll
    for (int mt = 0; mt < 8; ++mt) {
        const int tb  = t_wave + mt * 16;
        const int jlo = ibase + tb - MAXP;
        if (jlo + 30 < 0 || jlo >= LQ) continue;
        const int t = tb + n;                      // this lane's t
        #pragma unroll
        for (int s = 0; s < 4; ++s) {
            const int i = ibase + 4 * g + s;
            const int j = i + t - MAXP;
            if (t <= TT - 2 && j >= 0 && j < LQ)
                obase[(size_t)i * LQ + j] = acc[mt][s];
        }
    }
}

// Clamped triangles: left j in [0, i-512] = dot(Q[i],R[:,1]); right j in [i+512, 1023] = dot(Q[i],R[:,1023])
__global__ __launch_bounds__(256) void lpb_fill(const float* __restrict__ Q,
                                                const float* __restrict__ R,
                                                float* __restrict__ out) {
    const int w    = threadIdx.x >> 6;
    const int lane = threadIdx.x & 63;
    const int i    = blockIdx.x * 4 + w;
    const int nh   = blockIdx.y;
    const int h    = nh & (NH - 1);

    const float q  = Q[((size_t)nh * LQ + i) * DD + lane];
    const float r1 = R[((size_t)h * DD + lane) * TT + 1];
    const float r2 = R[((size_t)h * DD + lane) * TT + (TT - 2)];
    float p1 = q * r1;
    float p2 = q * r2;
    #pragma unroll
    for (int off = 32; off >= 1; off >>= 1) {
        p1 += __shfl_xor(p1, off, 64);
        p2 += __shfl_xor(p2, off, 64);
    }

    float* orow = out + ((size_t)nh * LQ + i) * LQ;
    for (int j = lane; j <= i - MAXP; j += 64) orow[j] = p1;
    for (int j = i + MAXP + lane; j < LQ; j += 64) orow[j] = p2;
}

extern "C" void kernel_launch(void* const* d_in, const int* in_sizes, int n_in,
                              void* d_out, int out_size, void* d_ws, size_t ws_size,
                              hipStream_t stream) {
    const float* Q = (const float*)d_in[0];
    const float* R = (const float*)d_in[1];
    float* out = (float*)d_out;

    lpb_main<<<dim3(2, 64, 64), 256, 0, stream>>>(Q, R, out);
    lpb_fill<<<dim3(LQ / 4, 64), 256, 0, stream>>>(Q, R, out);
}

// Round 3
// 93.545 us; speedup vs baseline: 1.9846x; 1.3792x over previous
//
#include <hip/hip_runtime.h>
#include <hip/hip_bf16.h>

// out[n,h,i,j] = sum_d Q[n,h,i,d] * R[h,d, clamp(j-i,-511,511)+512]
//             = logits[i][ clamp(j-i+512, 1, 1023) ]   (the clamp covers BOTH triangles)
// n=4 h=16 L=1024 d=64, table width 1025.
//
// One fused kernel: block = 16 rows (i) x all t. 4 waves compute logits[16][1024]
// via bf16 MFMA into LDS, then emit 16 complete 4KB-aligned output rows with a
// clamped LDS gather. All HBM writes are full aligned lines -> no RMW fetch.

#define NH 16
#define LQ 1024
#define DD 64
#define TT 1025
#define MAXP 512
#define LPAD 8
#define LSTRIDE (LQ + LPAD)   // 1032 floats; LDS = 16*1032*4 = 66 KB -> 2 blocks/CU

typedef float f32x4 __attribute__((ext_vector_type(4)));
typedef short s16x8 __attribute__((ext_vector_type(8)));

__device__ __forceinline__ short f2bf(float f) {
    __hip_bfloat16 h = __float2bfloat16(f);   // RNE
    return __builtin_bit_cast(short, h);
}

// grid: (i_tiles=64, nh=64), block 256 = 4 waves; wave w owns t in [256w, 256w+256)
__global__ __launch_bounds__(256, 2) void lpb_fused(const float* __restrict__ Q,
                                                    const float* __restrict__ R,
                                                    float* __restrict__ out) {
    __shared__ float lg[16][LSTRIDE];

    const int ib  = blockIdx.x;
    const int nh  = blockIdx.y;
    const int h   = nh & (NH - 1);
    const int tid = threadIdx.x;
    const int w   = tid >> 6;
    const int l   = tid & 63;
    const int n   = l & 15;    // A: i-local row; B: t-local col
    const int g   = l >> 4;    // k-chunk 8g..8g+7 (and +32)
    const int ibase = ib * 16;

    // ---- A fragments: lane holds Q[ibase+n][kh*32 + 8g + r], r=0..7
    const float* qrow = Q + ((size_t)nh * LQ + (ibase + n)) * DD + 8 * g;
    s16x8 qf[2];
    #pragma unroll
    for (int kh = 0; kh < 2; ++kh) {
        f32x4 a = *(const f32x4*)(qrow + kh * 32);
        f32x4 b = *(const f32x4*)(qrow + kh * 32 + 4);
        #pragma unroll
        for (int r = 0; r < 4; ++r) { qf[kh][r] = f2bf(a[r]); qf[kh][4 + r] = f2bf(b[r]); }
    }

    // ---- GEMM: 16 tiles of 16t each (wave covers 256 t), K=64 as 2x MFMA 16x16x32
    const float* rbase = R + (size_t)h * DD * TT + (size_t)(8 * g) * TT;
    #pragma unroll 4
    for (int mt = 0; mt < 16; ++mt) {
        const int tb = w * 256 + mt * 16;          // t in [0,1024); t=0 unused (clamp>=1)
        const float* rc = rbase + tb + n;
        s16x8 rf0, rf1;
        #pragma unroll
        for (int r = 0; r < 8; ++r) {
            rf0[r] = f2bf(rc[(size_t)r * TT]);
            rf1[r] = f2bf(rc[(size_t)(32 + r) * TT]);
        }
        f32x4 acc = (f32x4){0.f, 0.f, 0.f, 0.f};
        acc = __builtin_amdgcn_mfma_f32_16x16x32_bf16(qf[0], rf0, acc, 0, 0, 0);
        acc = __builtin_amdgcn_mfma_f32_16x16x32_bf16(qf[1], rf1, acc, 0, 0, 0);
        // D: col = n (t-local), row = 4g+s (i-local)
        #pragma unroll
        for (int s = 0; s < 4; ++s) lg[4 * g + s][tb + n] = acc[s];
    }
    __syncthreads();

    // ---- writer: wave w emits rows 4w..4w+3, full 4KB aligned contiguous rows
    #pragma unroll
    for (int rr = 0; rr < 4; ++rr) {
        const int il = 4 * w + rr;
        const int i  = ibase + il;
        float* orow = out + ((size_t)nh * LQ + i) * LQ;
        #pragma unroll
        for (int c = 0; c < 4; ++c) {
            const int j0 = c * 256 + 4 * l;
            f32x4 v;
            #pragma unroll
            for (int e = 0; e < 4; ++e) {
                int t = j0 + e - i + MAXP;
                t = t < 1 ? 1 : (t > TT - 2 ? TT - 2 : t);   // clamp to [1,1023]
                v[e] = lg[il][t];
            }
            *(f32x4*)(orow + j0) = v;
        }
    }
}

extern "C" void kernel_launch(void* const* d_in, const int* in_sizes, int n_in,
                              void* d_out, int out_size, void* d_ws, size_t ws_size,
                              hipStream_t stream) {
    const float* Q = (const float*)d_in[0];
    const float* R = (const float*)d_in[1];
    float* out = (float*)d_out;

    lpb_fused<<<dim3(64, 64), 256, 0, stream>>>(Q, R, out);
}